// Round 2
// baseline (269.479 us; speedup 1.0000x reference)
//
#include <hip/hip_runtime.h>
#include <string.h>

#define ALPHA 0.2f
// B=128, L=512, FIN=FOUT=128. All global I/O is FP32; internal GEMMs bf16 MFMA.

typedef short short8 __attribute__((ext_vector_type(8)));
typedef float floatx4 __attribute__((ext_vector_type(4)));
typedef unsigned short ushort8 __attribute__((ext_vector_type(8)));

__device__ inline unsigned short f2bf(float f) {
    unsigned int v; __builtin_memcpy(&v, &f, 4);
    v = v + 0x7FFFu + ((v >> 16) & 1u);   // round-to-nearest-even
    return (unsigned short)(v >> 16);
}
__device__ inline float bf2f(unsigned short u) {
    unsigned int v = ((unsigned int)u) << 16;
    float f; __builtin_memcpy(&f, &v, 4); return f;
}

// ---------------------------------------------------------------------------
// Kernel 1: Wh = h @ W  (fp32 in, bf16 MFMA, fp32 accum).
//  - writes Wh transposed per batch as bf16: wht[b][o][j]
//  - computes ei/ej from the FP32 accumulators (no bf16 rounding of Wh)
// grid 512 x 256 threads; each block does 128 rows (one (b, j-slice)).
// ---------------------------------------------------------------------------
__global__ __launch_bounds__(256) void wh_kernel(const float* __restrict__ h,
                                                 const float* __restrict__ W,
                                                 const float* __restrict__ a,
                                                 unsigned short* __restrict__ wht,
                                                 float* __restrict__ ei,
                                                 float* __restrict__ ej)
{
    __shared__ __align__(16) unsigned short w_t[128][136];   // [o][f] bf16, padded
    __shared__ __align__(16) unsigned short out_s[128][136]; // [j_local][o]
    const int tid  = threadIdx.x;
    const int lane = tid & 63;
    const int wv   = tid >> 6;
    const int quad = lane >> 4;
    const int l16  = lane & 15;
    const int r0   = blockIdx.x * 128;
    const int b    = r0 >> 9;
    const int jb   = r0 & 511;

    // Stage W transposed + bf16: W[f][o] -> w_t[o][f]
    for (int k = 0; k < 64; ++k) {
        int idx = k * 256 + tid;          // coalesced fp32 read
        w_t[idx & 127][idx >> 7] = f2bf(W[idx]);
    }
    // per-lane slices of attention vector a (fp32)
    float a1v[8], a2v[8];
    for (int n = 0; n < 8; ++n) {
        a1v[n] = a[n * 16 + l16];
        a2v[n] = a[128 + n * 16 + l16];
    }
    __syncthreads();

    floatx4 acc[2][8];
    for (int m = 0; m < 2; ++m)
        for (int n = 0; n < 8; ++n) acc[m][n] = (floatx4)0.f;

    for (int kk = 0; kk < 4; ++kk) {
        short8 afr[2];
        for (int m = 0; m < 2; ++m) {
            int r = r0 + wv * 32 + m * 16 + l16;
            const float* src = h + r * 128 + kk * 32 + quad * 8;
            short8 t;
            for (int e = 0; e < 8; ++e) t[e] = (short)f2bf(src[e]);
            afr[m] = t;
        }
        for (int n = 0; n < 8; ++n) {
            short8 bfr = *(const short8*)(&w_t[n * 16 + l16][kk * 32 + quad * 8]);
            for (int m = 0; m < 2; ++m)
                acc[m][n] = __builtin_amdgcn_mfma_f32_16x16x32_bf16(afr[m], bfr, acc[m][n], 0, 0, 0);
        }
    }

    // ---- ei/ej from fp32 accumulators ----
    // C layout: row = quad*4 + reg (per 16-tile), col = l16
    for (int m = 0; m < 2; ++m)
        for (int r = 0; r < 4; ++r) {
            float si = 0.f, sj = 0.f;
            for (int n = 0; n < 8; ++n) {
                float v = acc[m][n][r];
                si += v * a1v[n];
                sj += v * a2v[n];
            }
            for (int off = 8; off; off >>= 1) {
                si += __shfl_xor(si, off);
                sj += __shfl_xor(sj, off);
            }
            if (l16 == 0) {
                int il = wv * 32 + m * 16 + quad * 4 + r;
                ei[b * 512 + jb + il] = si;
                ej[b * 512 + jb + il] = sj;
            }
        }

    // ---- C -> bf16 -> LDS -> transposed write wht[b][o][j] ----
    for (int m = 0; m < 2; ++m)
        for (int n = 0; n < 8; ++n)
            for (int r = 0; r < 4; ++r)
                out_s[wv * 32 + m * 16 + quad * 4 + r][n * 16 + l16] = f2bf(acc[m][n][r]);
    __syncthreads();

    for (int it = 0; it < 8; ++it) {
        int vid = it * 256 + tid;
        int o   = vid >> 4;
        int jv  = (vid & 15) * 8;
        ushort8 tmp;
        for (int e = 0; e < 8; ++e) tmp[e] = out_s[jv + e][o];
        *(ushort8*)(wht + b * 65536 + o * 512 + jb + jv) = tmp;
    }
}

// ---------------------------------------------------------------------------
// Kernel 2: fused scores -> softmax -> att @ Wh -> elu.  fp32 bias/out.
// One block per (b, 32-row i-tile): grid 2048 x 256 threads.
// ---------------------------------------------------------------------------
__global__ __launch_bounds__(256) void attn_kernel(const unsigned short* __restrict__ wht,
                                                   const float* __restrict__ ei,
                                                   const float* __restrict__ ej,
                                                   const float* __restrict__ bias,
                                                   const int* __restrict__ adj,
                                                   float* __restrict__ out)
{
    __shared__ __align__(16) unsigned short p_s[32][520];    // unnormalized probs, bf16
    __shared__ __align__(16) unsigned short wh_s[128][136];  // Wh_t chunk: [o][k]
    __shared__ float ej_s[512];
    __shared__ float ei_s[32];
    __shared__ float s_row[32];

    const int tid  = threadIdx.x;
    const int lane = tid & 63;
    const int wv   = tid >> 6;
    const int quad = lane >> 4;
    const int l16  = lane & 15;
    const int b    = blockIdx.x >> 4;
    const int i0   = (blockIdx.x & 15) * 32;

    ej_s[tid]       = ej[b * 512 + tid];
    ej_s[256 + tid] = ej[b * 512 + 256 + tid];
    if (tid < 32) ei_s[tid] = ei[b * 512 + i0 + tid];
    __syncthreads();

    // ---- Phase A: scores + row softmax (one wave per row, full row in regs) ----
    for (int rr = 0; rr < 8; ++rr) {
        int il = wv * 8 + rr;
        int ig = i0 + il;
        float eiv = ei_s[il];
        const float* brow = bias + (size_t)(((b << 9) + ig)) * 512;
        const int* arow = adj + (ig << 9);
        float e8[8];
        float mx = -1e30f;
        for (int q = 0; q < 8; ++q) {
            int j = q * 64 + lane;
            float x = eiv + ej_s[j];
            x = x > 0.f ? x : ALPHA * x;          // leaky relu
            x += brow[j];                         // + edge bias (fp32)
            if (arow[j] == 0) x = -1e30f;         // mask
            e8[q] = x;
            mx = fmaxf(mx, x);
        }
        for (int off = 32; off; off >>= 1) mx = fmaxf(mx, __shfl_xor(mx, off));
        float sm = 0.f;
        for (int q = 0; q < 8; ++q) {
            float p = __expf(e8[q] - mx);         // masked -> 0
            p_s[il][q * 64 + lane] = f2bf(p);
            sm += p;
        }
        for (int off = 32; off; off >>= 1) sm += __shfl_xor(sm, off);
        if (lane == 0) s_row[il] = sm;
    }
    __syncthreads();

    // ---- Phase B: C[32x128] = P[32x512] @ Wh_b[512x128] via MFMA ----
    floatx4 acc[2][2];
    for (int m = 0; m < 2; ++m)
        for (int n = 0; n < 2; ++n) acc[m][n] = (floatx4)0.f;

    for (int kc = 0; kc < 4; ++kc) {
        __syncthreads();
        for (int it = 0; it < 8; ++it) {       // stage Wh_t chunk (16B rows)
            int vid = it * 256 + tid;
            int o   = vid >> 4;
            int jv  = (vid & 15) * 8;
            *(ushort8*)&wh_s[o][jv] =
                *(const ushort8*)(wht + b * 65536 + o * 512 + kc * 128 + jv);
        }
        __syncthreads();
        for (int ks = 0; ks < 4; ++ks) {
            int ko = ks * 32 + quad * 8;
            short8 af[2], bfv[2];
            for (int m = 0; m < 2; ++m)
                af[m] = *(const short8*)&p_s[m * 16 + l16][kc * 128 + ko];
            for (int n = 0; n < 2; ++n)
                bfv[n] = *(const short8*)&wh_s[wv * 32 + n * 16 + l16][ko];
            for (int m = 0; m < 2; ++m)
                for (int n = 0; n < 2; ++n)
                    acc[m][n] = __builtin_amdgcn_mfma_f32_16x16x32_bf16(af[m], bfv[n], acc[m][n], 0, 0, 0);
        }
    }

    // ---- Epilogue: normalize, elu, fp32 store ----
    for (int m = 0; m < 2; ++m)
        for (int n = 0; n < 2; ++n)
            for (int r = 0; r < 4; ++r) {
                int il = m * 16 + quad * 4 + r;
                int o  = wv * 32 + n * 16 + l16;
                float v = acc[m][n][r] / s_row[il];
                v = v > 0.f ? v : (__expf(v) - 1.f);   // elu
                out[(((b << 9) + i0 + il) << 7) + o] = v;
            }
}

// ---------------------------------------------------------------------------
extern "C" void kernel_launch(void* const* d_in, const int* in_sizes, int n_in,
                              void* d_out, int out_size, void* d_ws, size_t ws_size,
                              hipStream_t stream)
{
    const float* h    = (const float*)d_in[0]; // [128,512,128] fp32
    const float* W    = (const float*)d_in[1]; // [128,128] fp32
    const float* a    = (const float*)d_in[2]; // [256] fp32
    const float* bias = (const float*)d_in[3]; // [128,512,512] fp32
    const int*   adj  = (const int*)d_in[4];   // [512,512] int32 (bool)
    float*       out  = (float*)d_out;         // [128,512,128] fp32

    unsigned short* wht = (unsigned short*)d_ws;          // 16.78 MB bf16 Wh_t[b][o][j]
    float* ei = (float*)((char*)d_ws + 16777216);         // 256 KB
    float* ej = ei + 65536;                               // 256 KB

    hipLaunchKernelGGL(wh_kernel,   dim3(512),  dim3(256), 0, stream, h, W, a, wht, ei, ej);
    hipLaunchKernelGGL(attn_kernel, dim3(2048), dim3(256), 0, stream, wht, ei, ej, bias, adj, out);
}

// Round 3
// 264.104 us; speedup vs baseline: 1.0204x; 1.0204x over previous
//
#include <hip/hip_runtime.h>
#include <string.h>

#define ALPHA 0.2f
// B=128, L=512, FIN=FOUT=128. Global I/O fp32; internal GEMMs bf16 MFMA.

typedef short short8 __attribute__((ext_vector_type(8)));
typedef float floatx4 __attribute__((ext_vector_type(4)));
typedef int intx4 __attribute__((ext_vector_type(4)));
typedef unsigned short ushort4v __attribute__((ext_vector_type(4)));

__device__ inline unsigned short f2bf(float f) {
    unsigned int v; __builtin_memcpy(&v, &f, 4);
    v = v + 0x7FFFu + ((v >> 16) & 1u);   // RNE
    return (unsigned short)(v >> 16);
}

// ---------------------------------------------------------------------------
// Kernel 1: Wh^T = (h @ W)^T via swapped MFMA operands (A=W^T rows=o, B=h rows=j)
// -> C/D tile natively [o][j]: no LDS transpose. Also emits ei/ej from fp32 acc.
// grid 512 (one (b, 128-j slice) per block) x 256 threads.
// ---------------------------------------------------------------------------
__global__ __launch_bounds__(256) void wh_kernel(const float* __restrict__ h,
                                                 const float* __restrict__ W,
                                                 const float* __restrict__ a,
                                                 unsigned short* __restrict__ wht,
                                                 float* __restrict__ ei,
                                                 float* __restrict__ ej)
{
    __shared__ __align__(16) unsigned short h_s[128][136];  // [j_local][f] bf16
    __shared__ __align__(16) unsigned short w_s[128][136];  // [o][f] bf16
    __shared__ float a_s[256];
    const int tid  = threadIdx.x;
    const int lane = tid & 63;
    const int wv   = tid >> 6;
    const int quad = lane >> 4;
    const int l16  = lane & 15;
    const int r0   = blockIdx.x * 128;
    const int b    = r0 >> 9;
    const int jb   = r0 & 511;

    // Stage h tile (coalesced float4) -> bf16 LDS
    const float* hbase = h + (size_t)r0 * 128;
    for (int it = 0; it < 16; ++it) {
        int idx4 = it * 256 + tid;                 // float4 granule
        floatx4 v = *(const floatx4*)(hbase + idx4 * 4);
        int row = idx4 >> 5;
        int col = (idx4 & 31) * 4;
        ushort4v u;
        for (int e = 0; e < 4; ++e) u[e] = f2bf(v[e]);
        *(ushort4v*)&h_s[row][col] = u;
    }
    // Stage W transposed: W[f][o] -> w_s[o][f]
    for (int it = 0; it < 64; ++it) {
        int idx = it * 256 + tid;
        w_s[idx & 127][idx >> 7] = f2bf(W[idx]);
    }
    a_s[tid] = a[tid];
    __syncthreads();

    floatx4 acc[8][2];
    for (int mo = 0; mo < 8; ++mo)
        for (int n = 0; n < 2; ++n) acc[mo][n] = (floatx4)0.f;

    for (int kk = 0; kk < 4; ++kk) {
        short8 bfr[2];
        for (int n = 0; n < 2; ++n)
            bfr[n] = *(const short8*)&h_s[wv * 32 + n * 16 + l16][kk * 32 + quad * 8];
        for (int mo = 0; mo < 8; ++mo) {
            short8 afr = *(const short8*)&w_s[mo * 16 + l16][kk * 32 + quad * 8];
            acc[mo][0] = __builtin_amdgcn_mfma_f32_16x16x32_bf16(afr, bfr[0], acc[mo][0], 0, 0, 0);
            acc[mo][1] = __builtin_amdgcn_mfma_f32_16x16x32_bf16(afr, bfr[1], acc[mo][1], 0, 0, 0);
        }
    }

    // ei/ej from fp32 accumulators. D tile: row(o_local)=quad*4+r, col(j)=l16.
    for (int n = 0; n < 2; ++n) {
        float si = 0.f, sj = 0.f;
        for (int mo = 0; mo < 8; ++mo)
            for (int r = 0; r < 4; ++r) {
                int o = mo * 16 + quad * 4 + r;
                float v = acc[mo][n][r];
                si += v * a_s[o];
                sj += v * a_s[128 + o];
            }
        si += __shfl_xor(si, 16); si += __shfl_xor(si, 32);   // reduce over quad
        sj += __shfl_xor(sj, 16); sj += __shfl_xor(sj, 32);
        if (quad == 0) {
            int j = jb + wv * 32 + n * 16 + l16;
            ei[b * 512 + j] = si;
            ej[b * 512 + j] = sj;
        }
    }

    // wht[b][o][j] store (16-lane x 2B = 32B coalesced runs)
    for (int mo = 0; mo < 8; ++mo)
        for (int n = 0; n < 2; ++n)
            for (int r = 0; r < 4; ++r) {
                int o = mo * 16 + quad * 4 + r;
                int j = jb + wv * 32 + n * 16 + l16;
                wht[(size_t)b * 65536 + o * 512 + j] = f2bf(acc[mo][n][r]);
            }
}

// ---------------------------------------------------------------------------
// Kernel 2: scores -> softmax -> att @ Wh -> elu.
// One block per (b, 32-row i-tile): grid 2048 x 256. LDS ~33.6 KB -> 4 blk/CU.
// ---------------------------------------------------------------------------
__global__ __launch_bounds__(256, 4) void attn_kernel(const unsigned short* __restrict__ wht,
                                                      const float* __restrict__ ei,
                                                      const float* __restrict__ ej,
                                                      const float* __restrict__ bias,
                                                      const int* __restrict__ adj,
                                                      float* __restrict__ out)
{
    __shared__ __align__(16) unsigned short p_s[32][520];    // unnormalized probs
    __shared__ float ei_s[32];
    __shared__ float s_row[32];

    const int tid  = threadIdx.x;
    const int lane = tid & 63;
    const int wv   = tid >> 6;
    const int quad = lane >> 4;
    const int l16  = lane & 15;
    const int b    = blockIdx.x >> 4;
    const int i0   = (blockIdx.x & 15) * 32;

    // ej slice per lane: identical for every row -> registers, loaded once
    const floatx4 ejv0 = *(const floatx4*)(ej + b * 512 + lane * 4);
    const floatx4 ejv1 = *(const floatx4*)(ej + b * 512 + 256 + lane * 4);
    if (tid < 32) ei_s[tid] = ei[b * 512 + i0 + tid];
    __syncthreads();

    // ---- Phase A: one wave per row, software-pipelined over its 8 rows ----
    const float* bp = bias + ((size_t)(b * 512 + i0 + wv * 8)) * 512;
    const int*   ap = adj + (i0 + wv * 8) * 512;
    floatx4 bb0 = *(const floatx4*)(bp + lane * 4);
    floatx4 bb1 = *(const floatx4*)(bp + 256 + lane * 4);
    intx4   mm0 = *(const intx4*)(ap + lane * 4);
    intx4   mm1 = *(const intx4*)(ap + 256 + lane * 4);

    for (int rr = 0; rr < 8; ++rr) {
        floatx4 nb0, nb1; intx4 nm0, nm1;
        if (rr < 7) {                              // prefetch next row
            nb0 = *(const floatx4*)(bp + 512 + lane * 4);
            nb1 = *(const floatx4*)(bp + 768 + lane * 4);
            nm0 = *(const intx4*)(ap + 512 + lane * 4);
            nm1 = *(const intx4*)(ap + 768 + lane * 4);
        }
        const int il = wv * 8 + rr;
        const float eiv = ei_s[il];
        float xs[8];
        for (int e = 0; e < 4; ++e) {
            float x = eiv + ejv0[e];
            x = x > 0.f ? x : ALPHA * x;
            x += bb0[e];
            if (mm0[e] == 0) x = -1e30f;
            xs[e] = x;
        }
        for (int e = 0; e < 4; ++e) {
            float x = eiv + ejv1[e];
            x = x > 0.f ? x : ALPHA * x;
            x += bb1[e];
            if (mm1[e] == 0) x = -1e30f;
            xs[4 + e] = x;
        }
        float mx = xs[0];
        for (int e = 1; e < 8; ++e) mx = fmaxf(mx, xs[e]);
        for (int off = 32; off; off >>= 1) mx = fmaxf(mx, __shfl_xor(mx, off));
        float sm = 0.f;
        ushort4v p0, p1;
        for (int e = 0; e < 4; ++e) { float p = __expf(xs[e] - mx);     sm += p; p0[e] = f2bf(p); }
        for (int e = 0; e < 4; ++e) { float p = __expf(xs[4 + e] - mx); sm += p; p1[e] = f2bf(p); }
        *(ushort4v*)&p_s[il][lane * 4]       = p0;
        *(ushort4v*)&p_s[il][256 + lane * 4] = p1;
        for (int off = 32; off; off >>= 1) sm += __shfl_xor(sm, off);
        if (lane == 0) s_row[il] = sm;
        bb0 = nb0; bb1 = nb1; mm0 = nm0; mm1 = nm1;
        bp += 512; ap += 512;
    }
    __syncthreads();

    // ---- Phase B: C[32x128] = P[32x512] @ Wh[512x128], B-frags direct from L2 ----
    floatx4 acc[2][2];
    for (int m = 0; m < 2; ++m)
        for (int n = 0; n < 2; ++n) acc[m][n] = (floatx4)0.f;

    const unsigned short* wbase = wht + (size_t)b * 65536;
#pragma unroll 4
    for (int k16 = 0; k16 < 16; ++k16) {
        int ko = k16 * 32 + quad * 8;
        short8 af0 = *(const short8*)&p_s[l16][ko];
        short8 af1 = *(const short8*)&p_s[16 + l16][ko];
        short8 bf0 = *(const short8*)(wbase + (wv * 32 + l16) * 512 + ko);
        short8 bf1 = *(const short8*)(wbase + (wv * 32 + 16 + l16) * 512 + ko);
        acc[0][0] = __builtin_amdgcn_mfma_f32_16x16x32_bf16(af0, bf0, acc[0][0], 0, 0, 0);
        acc[0][1] = __builtin_amdgcn_mfma_f32_16x16x32_bf16(af0, bf1, acc[0][1], 0, 0, 0);
        acc[1][0] = __builtin_amdgcn_mfma_f32_16x16x32_bf16(af1, bf0, acc[1][0], 0, 0, 0);
        acc[1][1] = __builtin_amdgcn_mfma_f32_16x16x32_bf16(af1, bf1, acc[1][1], 0, 0, 0);
    }

    // ---- Epilogue: normalize, elu, fp32 store ----
    for (int m = 0; m < 2; ++m)
        for (int n = 0; n < 2; ++n)
            for (int r = 0; r < 4; ++r) {
                int il = m * 16 + quad * 4 + r;
                int o  = wv * 32 + n * 16 + l16;
                float v = acc[m][n][r] / s_row[il];
                v = v > 0.f ? v : (__expf(v) - 1.f);
                out[((size_t)(b * 512 + i0 + il)) * 128 + o] = v;
            }
}

// ---------------------------------------------------------------------------
extern "C" void kernel_launch(void* const* d_in, const int* in_sizes, int n_in,
                              void* d_out, int out_size, void* d_ws, size_t ws_size,
                              hipStream_t stream)
{
    const float* h    = (const float*)d_in[0];
    const float* W    = (const float*)d_in[1];
    const float* a    = (const float*)d_in[2];
    const float* bias = (const float*)d_in[3];
    const int*   adj  = (const int*)d_in[4];
    float*       out  = (float*)d_out;

    unsigned short* wht = (unsigned short*)d_ws;          // 16.78 MB bf16 Wh_t[b][o][j]
    float* ei = (float*)((char*)d_ws + 16777216);
    float* ej = ei + 65536;

    hipLaunchKernelGGL(wh_kernel,   dim3(512),  dim3(256), 0, stream, h, W, a, wht, ei, ej);
    hipLaunchKernelGGL(attn_kernel, dim3(2048), dim3(256), 0, stream, wht, ei, ej, bias, adj, out);
}

// Round 4
// 262.288 us; speedup vs baseline: 1.0274x; 1.0069x over previous
//
#include <hip/hip_runtime.h>
#include <string.h>

#define ALPHA 0.2f
// B=128, L=512, FIN=FOUT=128. Global I/O fp32; internal GEMMs bf16 MFMA.

typedef short short8 __attribute__((ext_vector_type(8)));
typedef float floatx4 __attribute__((ext_vector_type(4)));
typedef int intx4 __attribute__((ext_vector_type(4)));
typedef unsigned short ushort4v __attribute__((ext_vector_type(4)));

__device__ inline unsigned short f2bf(float f) {
    unsigned int v; __builtin_memcpy(&v, &f, 4);
    v = v + 0x7FFFu + ((v >> 16) & 1u);   // RNE
    return (unsigned short)(v >> 16);
}

// ---------------------------------------------------------------------------
// Kernel 1: Wh^T = (h @ W)^T via swapped MFMA operands (A=W^T rows=o, B=h rows=j)
// C/D tile natively [o][j]. Emits ei/ej from fp32 accumulators.
// grid 512 x 256 threads.
// ---------------------------------------------------------------------------
__global__ __launch_bounds__(256) void wh_kernel(const float* __restrict__ h,
                                                 const float* __restrict__ W,
                                                 const float* __restrict__ a,
                                                 unsigned short* __restrict__ wht,
                                                 float* __restrict__ ei,
                                                 float* __restrict__ ej)
{
    __shared__ __align__(16) unsigned short h_s[128][136];  // [j_local][f] bf16
    __shared__ __align__(16) unsigned short w_s[128][136];  // [o][f] bf16
    __shared__ float a_s[256];
    const int tid  = threadIdx.x;
    const int lane = tid & 63;
    const int wv   = tid >> 6;
    const int quad = lane >> 4;
    const int l16  = lane & 15;
    const int r0   = blockIdx.x * 128;
    const int b    = r0 >> 9;
    const int jb   = r0 & 511;

    const float* hbase = h + (size_t)r0 * 128;
    for (int it = 0; it < 16; ++it) {
        int idx4 = it * 256 + tid;
        floatx4 v = *(const floatx4*)(hbase + idx4 * 4);
        int row = idx4 >> 5;
        int col = (idx4 & 31) * 4;
        ushort4v u;
        for (int e = 0; e < 4; ++e) u[e] = f2bf(v[e]);
        *(ushort4v*)&h_s[row][col] = u;
    }
    for (int it = 0; it < 64; ++it) {
        int idx = it * 256 + tid;
        w_s[idx & 127][idx >> 7] = f2bf(W[idx]);
    }
    a_s[tid] = a[tid];
    __syncthreads();

    floatx4 acc[8][2];
    for (int mo = 0; mo < 8; ++mo)
        for (int n = 0; n < 2; ++n) acc[mo][n] = (floatx4)0.f;

    for (int kk = 0; kk < 4; ++kk) {
        short8 bfr[2];
        for (int n = 0; n < 2; ++n)
            bfr[n] = *(const short8*)&h_s[wv * 32 + n * 16 + l16][kk * 32 + quad * 8];
        for (int mo = 0; mo < 8; ++mo) {
            short8 afr = *(const short8*)&w_s[mo * 16 + l16][kk * 32 + quad * 8];
            acc[mo][0] = __builtin_amdgcn_mfma_f32_16x16x32_bf16(afr, bfr[0], acc[mo][0], 0, 0, 0);
            acc[mo][1] = __builtin_amdgcn_mfma_f32_16x16x32_bf16(afr, bfr[1], acc[mo][1], 0, 0, 0);
        }
    }

    for (int n = 0; n < 2; ++n) {
        float si = 0.f, sj = 0.f;
        for (int mo = 0; mo < 8; ++mo)
            for (int r = 0; r < 4; ++r) {
                int o = mo * 16 + quad * 4 + r;
                float v = acc[mo][n][r];
                si += v * a_s[o];
                sj += v * a_s[128 + o];
            }
        si += __shfl_xor(si, 16); si += __shfl_xor(si, 32);
        sj += __shfl_xor(sj, 16); sj += __shfl_xor(sj, 32);
        if (quad == 0) {
            int j = jb + wv * 32 + n * 16 + l16;
            ei[b * 512 + j] = si;
            ej[b * 512 + j] = sj;
        }
    }

    for (int mo = 0; mo < 8; ++mo)
        for (int n = 0; n < 2; ++n)
            for (int r = 0; r < 4; ++r) {
                int o = mo * 16 + quad * 4 + r;
                int j = jb + wv * 32 + n * 16 + l16;
                wht[(size_t)b * 65536 + o * 512 + j] = f2bf(acc[mo][n][r]);
            }
}

// ---------------------------------------------------------------------------
// Kernel 2: scores -> softmax (no max-sub, deferred sums) -> att @ Wh -> elu.
// One block per (b, 32-row i-tile): grid 2048 x 256. LDS ~33.8 KB -> 4 blk/CU.
// ---------------------------------------------------------------------------
__global__ __launch_bounds__(256, 4) void attn_kernel(const unsigned short* __restrict__ wht,
                                                      const float* __restrict__ ei,
                                                      const float* __restrict__ ej,
                                                      const float* __restrict__ bias,
                                                      const int* __restrict__ adj,
                                                      float* __restrict__ out)
{
    __shared__ __align__(16) unsigned short p_s[32][520];    // unnormalized probs
    __shared__ float ei_s[32];
    __shared__ float s_row[32];

    const int tid  = threadIdx.x;
    const int lane = tid & 63;
    const int wv   = tid >> 6;
    const int quad = lane >> 4;
    const int l16  = lane & 15;
    const int b    = blockIdx.x >> 4;
    const int i0   = (blockIdx.x & 15) * 32;

    const floatx4 ejv0 = *(const floatx4*)(ej + b * 512 + lane * 4);
    const floatx4 ejv1 = *(const floatx4*)(ej + b * 512 + 256 + lane * 4);
    if (tid < 32) ei_s[tid] = ei[b * 512 + i0 + tid];
    __syncthreads();

    // ---- Phase A: one wave per 8 rows; no per-row wave-wide sync points ----
    const float* bp = bias + ((size_t)(b * 512 + i0 + wv * 8)) * 512;
    const int*   ap = adj + (i0 + wv * 8) * 512;
    floatx4 bb0 = *(const floatx4*)(bp + lane * 4);
    floatx4 bb1 = *(const floatx4*)(bp + 256 + lane * 4);
    intx4   mm0 = *(const intx4*)(ap + lane * 4);
    intx4   mm1 = *(const intx4*)(ap + 256 + lane * 4);

    float rsum[8];   // per-lane partial sum for each of this wave's 8 rows

#pragma unroll
    for (int rr = 0; rr < 8; ++rr) {
        floatx4 nb0, nb1; intx4 nm0, nm1;
        if (rr < 7) {                              // prefetch next row
            nb0 = *(const floatx4*)(bp + 512 + lane * 4);
            nb1 = *(const floatx4*)(bp + 768 + lane * 4);
            nm0 = *(const intx4*)(ap + 512 + lane * 4);
            nm1 = *(const intx4*)(ap + 768 + lane * 4);
        }
        const int il = wv * 8 + rr;
        const float eiv = ei_s[il];
        float sm = 0.f;
        ushort4v p0, p1;
        for (int e = 0; e < 4; ++e) {
            float x = eiv + ejv0[e];
            x = fmaxf(x, ALPHA * x);               // leaky relu (1 max)
            x += bb0[e];
            float p = __expf(x);                   // no max-subtraction (|x| small)
            p = (mm0[e] != 0) ? p : 0.f;
            sm += p;
            p0[e] = f2bf(p);
        }
        for (int e = 0; e < 4; ++e) {
            float x = eiv + ejv1[e];
            x = fmaxf(x, ALPHA * x);
            x += bb1[e];
            float p = __expf(x);
            p = (mm1[e] != 0) ? p : 0.f;
            sm += p;
            p1[e] = f2bf(p);
        }
        *(ushort4v*)&p_s[il][lane * 4]       = p0;
        *(ushort4v*)&p_s[il][256 + lane * 4] = p1;
        rsum[rr] = sm;
        bb0 = nb0; bb1 = nb1; mm0 = nm0; mm1 = nm1;
        bp += 512; ap += 512;
    }

    // Deferred row-sum reductions: 8 independent trees, pipelined
#pragma unroll
    for (int rr = 0; rr < 8; ++rr)
        for (int off = 32; off; off >>= 1)
            rsum[rr] += __shfl_xor(rsum[rr], off);
    if (lane == 0)
#pragma unroll
        for (int rr = 0; rr < 8; ++rr) s_row[wv * 8 + rr] = rsum[rr];
    __syncthreads();

    // ---- Phase B: C[32x128] = P[32x512] @ Wh[512x128], B-frags from L2, prefetched ----
    floatx4 acc[2][2];
    for (int m = 0; m < 2; ++m)
        for (int n = 0; n < 2; ++n) acc[m][n] = (floatx4)0.f;

    const unsigned short* wbase = wht + (size_t)b * 65536;
    const unsigned short* wb0 = wbase + (wv * 32 + l16) * 512 + quad * 8;
    const unsigned short* wb1 = wbase + (wv * 32 + 16 + l16) * 512 + quad * 8;
    short8 bf0 = *(const short8*)(wb0);
    short8 bf1 = *(const short8*)(wb1);
#pragma unroll
    for (int k16 = 0; k16 < 16; ++k16) {
        int ko = k16 * 32 + quad * 8;
        short8 nbf0, nbf1;
        if (k16 < 15) {
            nbf0 = *(const short8*)(wb0 + (k16 + 1) * 32);
            nbf1 = *(const short8*)(wb1 + (k16 + 1) * 32);
        }
        short8 af0 = *(const short8*)&p_s[l16][ko];
        short8 af1 = *(const short8*)&p_s[16 + l16][ko];
        acc[0][0] = __builtin_amdgcn_mfma_f32_16x16x32_bf16(af0, bf0, acc[0][0], 0, 0, 0);
        acc[0][1] = __builtin_amdgcn_mfma_f32_16x16x32_bf16(af0, bf1, acc[0][1], 0, 0, 0);
        acc[1][0] = __builtin_amdgcn_mfma_f32_16x16x32_bf16(af1, bf0, acc[1][0], 0, 0, 0);
        acc[1][1] = __builtin_amdgcn_mfma_f32_16x16x32_bf16(af1, bf1, acc[1][1], 0, 0, 0);
        bf0 = nbf0; bf1 = nbf1;
    }

    // ---- Epilogue: normalize, elu, fp32 store ----
    for (int m = 0; m < 2; ++m)
        for (int n = 0; n < 2; ++n)
            for (int r = 0; r < 4; ++r) {
                int il = m * 16 + quad * 4 + r;
                int o  = wv * 32 + n * 16 + l16;
                float v = acc[m][n][r] / s_row[il];
                v = v > 0.f ? v : (__expf(v) - 1.f);
                out[((size_t)(b * 512 + i0 + il)) * 128 + o] = v;
            }
}

// ---------------------------------------------------------------------------
extern "C" void kernel_launch(void* const* d_in, const int* in_sizes, int n_in,
                              void* d_out, int out_size, void* d_ws, size_t ws_size,
                              hipStream_t stream)
{
    const float* h    = (const float*)d_in[0];
    const float* W    = (const float*)d_in[1];
    const float* a    = (const float*)d_in[2];
    const float* bias = (const float*)d_in[3];
    const int*   adj  = (const int*)d_in[4];
    float*       out  = (float*)d_out;

    unsigned short* wht = (unsigned short*)d_ws;          // 16.78 MB bf16 Wh_t[b][o][j]
    float* ei = (float*)((char*)d_ws + 16777216);
    float* ej = ei + 65536;

    hipLaunchKernelGGL(wh_kernel,   dim3(512),  dim3(256), 0, stream, h, W, a, wht, ei, ej);
    hipLaunchKernelGGL(attn_kernel, dim3(2048), dim3(256), 0, stream, wht, ei, ej, bias, adj, out);
}